// Round 2
// baseline (489.800 us; speedup 1.0000x reference)
//
#include <hip/hip_runtime.h>

typedef float v4f __attribute__((ext_vector_type(4)));
typedef float v2f __attribute__((ext_vector_type(2)));

// Problem constants: B=64, S=1024, H=1000.
constexpr int Bb = 64;
constexpr int Ss = 1024;
constexpr int Hh = 1000;
constexpr int CHUNKS = 32;          // s-chunks per batch (one wave each)
constexpr int CS = Ss / CHUNKS;     // 32 positions per wave
constexpr int BG = 4;               // batches per proj block
constexpr int PW = 8;               // g-split waves per proj block
constexpr int GL = Hh / PW;         // 125 g per wave
constexpr int BLK_PER_B = CHUNKS / 4;  // 8 attn blocks per batch

// Kernel 1: u[b] = W^T h_tgt[b]. Grid (16 b-groups, 8 v2f-slot-groups) x 512.
// h_tgt slice staged in LDS (kills per-iter scalar global loads); W loads
// unrolled 8-deep for latency hiding. Also zero-inits the per-batch counters
// used by the fused attn+combine kernel (visible via kernel boundary).
__global__ __launch_bounds__(512) void proj_tgt_kernel(
    const float* __restrict__ h_tgt, const float* __restrict__ W,
    float* __restrict__ u, int* __restrict__ counters)
{
    const int tid  = (int)threadIdx.x;
    const int lane = tid & 63;
    const int w    = tid >> 6;                     // g-split wave id [0,8)
    const int b0   = (int)blockIdx.x * BG;
    const int slot = (int)blockIdx.y * 64 + lane;  // v2f slot in [0,500)
    const bool ok  = (slot < Hh / 2);
    const int h    = slot * 2;

    if (blockIdx.x == 0 && blockIdx.y == 0 && tid < Bb) counters[tid] = 0;

    __shared__ float sA[BG * Hh];                  // 16 KB: h_tgt[b0..b0+3]
    for (int i = tid; i < BG * Hh; i += 512) sA[i] = h_tgt[b0 * Hh + i];
    __syncthreads();

    v2f acc[BG];
    #pragma unroll
    for (int bi = 0; bi < BG; ++bi) acc[bi] = (v2f){0.f, 0.f};

    const int gbase = w * GL;
    const float* wp = W + (size_t)gbase * Hh + h;
    #pragma unroll 8
    for (int g = 0; g < GL; ++g) {
        const v2f w2 = ok ? *(const v2f*)wp : (v2f){0.f, 0.f};
        #pragma unroll
        for (int bi = 0; bi < BG; ++bi)
            acc[bi] += sA[bi * Hh + gbase + g] * w2;   // LDS broadcast
        wp += Hh;
    }
    __syncthreads();                               // sA dead; reuse LDS below

    __shared__ v2f red[BG][PW][64];                // 16 KiB
    #pragma unroll
    for (int bi = 0; bi < BG; ++bi) red[bi][w][lane] = acc[bi];
    __syncthreads();

    // waves 0..3: wave w reduces batch b0+w across the 8 g-splits
    if (w < BG) {
        v2f s = red[w][0][lane];
        #pragma unroll
        for (int p = 1; p < PW; ++p) s += red[w][p][lane];
        if (ok) *(v2f*)(u + (size_t)(b0 + w) * Hh + h) = s;
    }
}

// Kernel 2: fused score + online softmax + weighted accumulation + per-batch
// merge. One wave per (b, s-chunk of 32); each block = 4 chunks of ONE batch
// (8 blocks/batch). Last block of a batch (device-scope atomic counter) merges
// the 32 chunk-partials -> out[b], overlapping other batches' attn tails.
__global__ __launch_bounds__(256) void attn_kernel(
    const float* __restrict__ h_src, const float* __restrict__ u,
    float* __restrict__ wsM, float* __restrict__ wsL, float* __restrict__ wsC,
    int* __restrict__ counters, float* __restrict__ out)
{
    const int lane  = threadIdx.x & 63;
    const int wave  = (int)((blockIdx.x * blockDim.x + threadIdx.x) >> 6);
    const int b     = wave >> 5;      // uniform per block (8 blocks per batch)
    const int chunk = wave & 31;
    const int s0    = chunk * CS;

    const float* ub = u + b * Hh;
    v4f uf[4];
    #pragma unroll
    for (int j = 0; j < 4; ++j) {
        const int d = j * 256 + lane * 4;
        uf[j] = (d < Hh) ? *(const v4f*)(ub + d) : (v4f){0.f, 0.f, 0.f, 0.f};
    }

    float m = -INFINITY, l = 0.f;
    v4f c[4];
    #pragma unroll
    for (int j = 0; j < 4; ++j) c[j] = (v4f){0.f, 0.f, 0.f, 0.f};

    const float* xp = h_src + (size_t)(b * Ss + s0) * Hh;
    for (int s = 0; s < CS; s += 4) {
        v4f x[4][4];                  // [row][j]
        #pragma unroll
        for (int r = 0; r < 4; ++r) {
            #pragma unroll
            for (int j = 0; j < 4; ++j) {
                const int d = j * 256 + lane * 4;
                x[r][j] = (d < Hh)
                    ? __builtin_nontemporal_load((const v4f*)(xp + (size_t)r * Hh + d))
                    : (v4f){0.f, 0.f, 0.f, 0.f};
            }
        }
        float p[4] = {0.f, 0.f, 0.f, 0.f};
        #pragma unroll
        for (int r = 0; r < 4; ++r) {
            #pragma unroll
            for (int j = 0; j < 4; ++j) {
                p[r] = fmaf(x[r][j].x, uf[j].x, p[r]);
                p[r] = fmaf(x[r][j].y, uf[j].y, p[r]);
                p[r] = fmaf(x[r][j].z, uf[j].z, p[r]);
                p[r] = fmaf(x[r][j].w, uf[j].w, p[r]);
            }
        }
        // four interleaved 64-lane butterflies
        #pragma unroll
        for (int off = 32; off > 0; off >>= 1) {
            #pragma unroll
            for (int r = 0; r < 4; ++r) p[r] += __shfl_xor(p[r], off, 64);
        }

        const float mx01 = fmaxf(p[0], p[1]);
        const float mx23 = fmaxf(p[2], p[3]);
        const float mn = fmaxf(m, fmaxf(mx01, mx23));
        if (mn > m) {                            // wave-uniform branch
            const float scale = __expf(m - mn);  // first iter: exp(-inf)=0
            m = mn;
            l *= scale;
            #pragma unroll
            for (int j = 0; j < 4; ++j) c[j] *= scale;
        }
        float e[4];
        #pragma unroll
        for (int r = 0; r < 4; ++r) e[r] = __expf(p[r] - m);
        l += (e[0] + e[1]) + (e[2] + e[3]);
        #pragma unroll
        for (int r = 0; r < 4; ++r) {
            #pragma unroll
            for (int j = 0; j < 4; ++j) {
                c[j].x = fmaf(e[r], x[r][j].x, c[j].x);
                c[j].y = fmaf(e[r], x[r][j].y, c[j].y);
                c[j].z = fmaf(e[r], x[r][j].z, c[j].z);
                c[j].w = fmaf(e[r], x[r][j].w, c[j].w);
            }
        }
        xp += 4 * Hh;
    }

    const int idx = b * CHUNKS + chunk;
    if (lane == 0) { wsM[idx] = m; wsL[idx] = l; }
    float* cw = wsC + (size_t)idx * Hh;
    #pragma unroll
    for (int j = 0; j < 4; ++j) {
        const int d = j * 256 + lane * 4;
        if (d < Hh) *(v4f*)(cw + d) = c[j];   // L2-resident for the merge
    }

    // --- per-batch merge by the last-arriving block of this batch ---
    __threadfence();                          // release our wsM/wsL/wsC writes
    __syncthreads();                          // all 4 waves of block done
    __shared__ int sLast;
    if (threadIdx.x == 0) {
        const int prev = atomicAdd(&counters[b], 1);   // device-scope
        sLast = (prev == BLK_PER_B - 1);
    }
    __syncthreads();
    if (!sLast) return;
    __threadfence();                          // acquire side before re-reads

    __shared__ float sw[CHUNKS];
    __shared__ float sInvL;
    const int tid = (int)threadIdx.x;
    if (tid < 64) {   // wave 0: lanes 0..31 = chunks, 32..63 neutral
        const bool v = (tid < CHUNKS);
        const float mi = v ? wsM[b * CHUNKS + tid] : -INFINITY;
        const float li = v ? wsL[b * CHUNKS + tid] : 0.f;
        float M = mi;
        #pragma unroll
        for (int off = 32; off > 0; off >>= 1) M = fmaxf(M, __shfl_xor(M, off, 64));
        const float w2 = __expf(mi - M);
        float L = w2 * li;
        #pragma unroll
        for (int off = 32; off > 0; off >>= 1) L += __shfl_xor(L, off, 64);
        if (v) sw[tid] = w2;
        if (tid == 0) sInvL = 1.f / L;
    }
    __syncthreads();

    if (tid < 250) {                          // 250 float4 slots
        const int h = tid * 4;
        v4f acc = (v4f){0.f, 0.f, 0.f, 0.f};
        #pragma unroll 8
        for (int i = 0; i < CHUNKS; ++i)
            acc += sw[i] * *(const v4f*)(wsC + (size_t)(b * CHUNKS + i) * Hh + h);
        *(v4f*)(out + b * Hh + h) = acc * sInvL;
    }
}

extern "C" void kernel_launch(void* const* d_in, const int* in_sizes, int n_in,
                              void* d_out, int out_size, void* d_ws, size_t ws_size,
                              hipStream_t stream) {
    const float* h_tgt = (const float*)d_in[0];
    const float* h_src = (const float*)d_in[1];
    const float* W     = (const float*)d_in[2];
    // bias (d_in[3]) unused: h_tgt . bias is constant over s -> cancels in softmax.
    float* out = (float*)d_out;

    // ws floats: u[64000] | wsM[2048] | wsL[2048] | wsC[2048000] | counters[64]
    float* u   = (float*)d_ws;
    float* wsM = u + Bb * Hh;
    float* wsL = wsM + Bb * CHUNKS;
    float* wsC = wsL + Bb * CHUNKS;          // float offset 68096 (16B aligned)
    int*   ctr = (int*)(wsC + (size_t)Bb * CHUNKS * Hh);

    proj_tgt_kernel<<<dim3(Bb / BG, 8), 512, 0, stream>>>(h_tgt, W, u, ctr);
    attn_kernel<<<(Bb * CHUNKS) / 4, 256, 0, stream>>>(h_src, u, wsM, wsL, wsC, ctr, out);
}

// Round 3
// 360.088 us; speedup vs baseline: 1.3602x; 1.3602x over previous
//
#include <hip/hip_runtime.h>

typedef float v4f __attribute__((ext_vector_type(4)));
typedef float v2f __attribute__((ext_vector_type(2)));

// Problem constants: B=64, S=1024, H=1000.
constexpr int Bb = 64;
constexpr int Ss = 1024;
constexpr int Hh = 1000;
constexpr int CHUNKS = 32;          // s-chunks per batch (one wave each)
constexpr int CS = Ss / CHUNKS;     // 32 positions per wave
constexpr int BG = 4;               // batches per proj block
constexpr int PW = 8;               // g-split waves per proj block
constexpr int GL = Hh / PW;         // 125 g per wave

// Kernel 1: u[b] = W^T h_tgt[b]. Grid (16 b-groups, 8 v2f-slot-groups) x 512.
// h_tgt slice staged in LDS (kills per-iter wave-uniform global loads); W load
// loop unrolled 8-deep so ~8 dwordx2 are in flight per wave (latency hiding).
// NOTE (R2 post-mortem): do NOT fuse the softmax merge into the attn kernel
// via device-scope fences — __threadfence() on gfx950 = L2 wb/inv per wave,
// and 512 blocks' staggered fences trash the L2/L3 h_src stream (-117 us).
__global__ __launch_bounds__(512) void proj_tgt_kernel(
    const float* __restrict__ h_tgt, const float* __restrict__ W,
    float* __restrict__ u)
{
    const int tid  = (int)threadIdx.x;
    const int lane = tid & 63;
    const int w    = tid >> 6;                     // g-split wave id [0,8)
    const int b0   = (int)blockIdx.x * BG;
    const int slot = (int)blockIdx.y * 64 + lane;  // v2f slot in [0,500)
    const bool ok  = (slot < Hh / 2);
    const int h    = slot * 2;

    __shared__ float sA[BG * Hh];                  // 16 KB: h_tgt[b0..b0+3]
    for (int i = tid; i < BG * Hh; i += 512) sA[i] = h_tgt[b0 * Hh + i];
    __syncthreads();

    v2f acc[BG];
    #pragma unroll
    for (int bi = 0; bi < BG; ++bi) acc[bi] = (v2f){0.f, 0.f};

    const int gbase = w * GL;
    const float* wp = W + (size_t)gbase * Hh + h;
    #pragma unroll 8
    for (int g = 0; g < GL; ++g) {
        const v2f w2 = ok ? *(const v2f*)wp : (v2f){0.f, 0.f};
        #pragma unroll
        for (int bi = 0; bi < BG; ++bi)
            acc[bi] += sA[bi * Hh + gbase + g] * w2;   // LDS broadcast
        wp += Hh;
    }
    __syncthreads();                               // sA dead; reuse LDS below

    __shared__ v2f red[BG][PW][64];                // 16 KiB
    #pragma unroll
    for (int bi = 0; bi < BG; ++bi) red[bi][w][lane] = acc[bi];
    __syncthreads();

    // waves 0..3: wave w reduces batch b0+w across the 8 g-splits
    if (w < BG) {
        v2f s = red[w][0][lane];
        #pragma unroll
        for (int p = 1; p < PW; ++p) s += red[w][p][lane];
        if (ok) *(v2f*)(u + (size_t)(b0 + w) * Hh + h) = s;
    }
}

// Kernel 2: fused score + online softmax + weighted accumulation.
// One wave per (b, s-chunk of 32); 2048 waves (8/CU). 4 s-rows per macro-iter
// -> 16 dwordx4 loads in flight per wave, 4 interleaved shuffle/exp chains.
// BW-bound: per-CU VALU demand ~15-20x below stream service rate.
__global__ __launch_bounds__(256) void attn_partial_kernel(
    const float* __restrict__ h_src, const float* __restrict__ u,
    float* __restrict__ wsM, float* __restrict__ wsL, float* __restrict__ wsC)
{
    const int lane  = threadIdx.x & 63;
    const int wave  = (int)((blockIdx.x * blockDim.x + threadIdx.x) >> 6);
    const int b     = wave >> 5;      // / CHUNKS
    const int chunk = wave & 31;      // % CHUNKS
    const int s0    = chunk * CS;

    const float* ub = u + b * Hh;
    v4f uf[4];
    #pragma unroll
    for (int j = 0; j < 4; ++j) {
        const int d = j * 256 + lane * 4;
        uf[j] = (d < Hh) ? *(const v4f*)(ub + d) : (v4f){0.f, 0.f, 0.f, 0.f};
    }

    float m = -INFINITY, l = 0.f;
    v4f c[4];
    #pragma unroll
    for (int j = 0; j < 4; ++j) c[j] = (v4f){0.f, 0.f, 0.f, 0.f};

    const float* xp = h_src + (size_t)(b * Ss + s0) * Hh;
    for (int s = 0; s < CS; s += 4) {
        v4f x[4][4];                  // [row][j]
        #pragma unroll
        for (int r = 0; r < 4; ++r) {
            #pragma unroll
            for (int j = 0; j < 4; ++j) {
                const int d = j * 256 + lane * 4;
                x[r][j] = (d < Hh)
                    ? __builtin_nontemporal_load((const v4f*)(xp + (size_t)r * Hh + d))
                    : (v4f){0.f, 0.f, 0.f, 0.f};
            }
        }
        float p[4] = {0.f, 0.f, 0.f, 0.f};
        #pragma unroll
        for (int r = 0; r < 4; ++r) {
            #pragma unroll
            for (int j = 0; j < 4; ++j) {
                p[r] = fmaf(x[r][j].x, uf[j].x, p[r]);
                p[r] = fmaf(x[r][j].y, uf[j].y, p[r]);
                p[r] = fmaf(x[r][j].z, uf[j].z, p[r]);
                p[r] = fmaf(x[r][j].w, uf[j].w, p[r]);
            }
        }
        // four interleaved 64-lane butterflies
        #pragma unroll
        for (int off = 32; off > 0; off >>= 1) {
            #pragma unroll
            for (int r = 0; r < 4; ++r) p[r] += __shfl_xor(p[r], off, 64);
        }

        const float mx01 = fmaxf(p[0], p[1]);
        const float mx23 = fmaxf(p[2], p[3]);
        const float mn = fmaxf(m, fmaxf(mx01, mx23));
        if (mn > m) {                            // wave-uniform branch
            const float scale = __expf(m - mn);  // first iter: exp(-inf)=0
            m = mn;
            l *= scale;
            #pragma unroll
            for (int j = 0; j < 4; ++j) c[j] *= scale;
        }
        float e[4];
        #pragma unroll
        for (int r = 0; r < 4; ++r) e[r] = __expf(p[r] - m);
        l += (e[0] + e[1]) + (e[2] + e[3]);
        #pragma unroll
        for (int r = 0; r < 4; ++r) {
            #pragma unroll
            for (int j = 0; j < 4; ++j) {
                c[j].x = fmaf(e[r], x[r][j].x, c[j].x);
                c[j].y = fmaf(e[r], x[r][j].y, c[j].y);
                c[j].z = fmaf(e[r], x[r][j].z, c[j].z);
                c[j].w = fmaf(e[r], x[r][j].w, c[j].w);
            }
        }
        xp += 4 * Hh;
    }

    const int idx = b * CHUNKS + chunk;
    if (lane == 0) { wsM[idx] = m; wsL[idx] = l; }
    float* cw = wsC + (size_t)idx * Hh;
    #pragma unroll
    for (int j = 0; j < 4; ++j) {
        const int d = j * 256 + lane * 4;
        if (d < Hh) *(v4f*)(cw + d) = c[j];   // cached: combine re-reads from L2
    }
}

// Kernel 3: merge 32 chunk-partials per batch. Grid (64 b, 2 h-halves) x 128.
// Each half-block owns 125 float4 slots -> 2x CU coverage and half the serial
// accumulation depth vs a single-block-per-batch merge.
__global__ __launch_bounds__(128) void combine_kernel(
    const float* __restrict__ wsM, const float* __restrict__ wsL,
    const float* __restrict__ wsC, float* __restrict__ out)
{
    const int b    = (int)blockIdx.x;
    const int half = (int)blockIdx.y;
    const int tid  = (int)threadIdx.x;
    __shared__ float sw[CHUNKS];
    __shared__ float sInvL;

    if (tid < 64) {   // wave 0: lanes 0..31 = chunks, 32..63 neutral
        const bool v = (tid < CHUNKS);
        const float mi = v ? wsM[b * CHUNKS + tid] : -INFINITY;
        const float li = v ? wsL[b * CHUNKS + tid] : 0.f;
        float M = mi;
        #pragma unroll
        for (int off = 32; off > 0; off >>= 1) M = fmaxf(M, __shfl_xor(M, off, 64));
        const float w = __expf(mi - M);
        float L = w * li;
        #pragma unroll
        for (int off = 32; off > 0; off >>= 1) L += __shfl_xor(L, off, 64);
        if (v) sw[tid] = w;
        if (tid == 0) sInvL = 1.f / L;
    }
    __syncthreads();

    const int slot = half * 125 + tid;        // float4 slot in [0,250)
    if (tid < 125) {
        const int h = slot * 4;
        v4f acc = (v4f){0.f, 0.f, 0.f, 0.f};
        #pragma unroll 8
        for (int i = 0; i < CHUNKS; ++i)
            acc += sw[i] * *(const v4f*)(wsC + (size_t)(b * CHUNKS + i) * Hh + h);
        *(v4f*)(out + b * Hh + h) = acc * sInvL;
    }
}

extern "C" void kernel_launch(void* const* d_in, const int* in_sizes, int n_in,
                              void* d_out, int out_size, void* d_ws, size_t ws_size,
                              hipStream_t stream) {
    const float* h_tgt = (const float*)d_in[0];
    const float* h_src = (const float*)d_in[1];
    const float* W     = (const float*)d_in[2];
    // bias (d_in[3]) unused: h_tgt . bias is constant over s -> cancels in softmax.
    float* out = (float*)d_out;

    // ws floats: u[64000] | wsM[2048] | wsL[2048] | wsC[2048000]
    float* u   = (float*)d_ws;
    float* wsM = u + Bb * Hh;
    float* wsL = wsM + Bb * CHUNKS;
    float* wsC = wsL + Bb * CHUNKS;          // float offset 68096 (16B aligned)

    proj_tgt_kernel<<<dim3(Bb / BG, 8), 512, 0, stream>>>(h_tgt, W, u);
    attn_partial_kernel<<<(Bb * CHUNKS) / 4, 256, 0, stream>>>(h_src, u, wsM, wsL, wsC);
    combine_kernel<<<dim3(Bb, 2), 128, 0, stream>>>(wsM, wsL, wsC, out);
}